// Round 8
// baseline (171.278 us; speedup 1.0000x reference)
//
#include <hip/hip_runtime.h>
#include <hip/hip_bf16.h>

// LocalAttention: BK=64 swizzled 128^2 bf16 MFMA GEMMs + LDS-free MFMA flash attn.
// ws layout (bytes): xb[0,8M) w1b[8M,14M) wob[14M,16M) Q[16M,24M) K[24M,32M)
//                    VT[32M,40M) attn[40M,48M)   -- all bf16 (short)

#define S_LEN 2048
#define NH 16
#define DH 64
#define DM 1024
#define WIN 128
#define K_DIM 1024

typedef __attribute__((ext_vector_type(8))) short short8;
typedef __attribute__((ext_vector_type(4))) short short4_t;
typedef __attribute__((ext_vector_type(4))) float f32x4;
typedef __attribute__((ext_vector_type(16))) float f32x16;

__device__ __forceinline__ unsigned short f2bf(float f){
  unsigned u = __float_as_uint(f);
  u += 0x7fffu + ((u >> 16) & 1u);   // RTNE
  return (unsigned short)(u >> 16);
}
__device__ __forceinline__ unsigned pk2(float lo, float hi){
  __hip_bfloat162 h = __float22bfloat162_rn(float2{lo, hi});
  return *reinterpret_cast<unsigned*>(&h);   // v_cvt_pk_bf16_f32
}
__device__ __forceinline__ void async16(void* l, const void* g){
  __builtin_amdgcn_global_load_lds((const __attribute__((address_space(1))) void*)g,
                                   (__attribute__((address_space(3))) void*)l, 16, 0, 0);
}

// ---------------- fused fp32->bf16 converts (exact ranges, no tail)
__global__ void cvt_all(const float* __restrict__ x, const float* __restrict__ w1,
                        const float* __restrict__ wo,
                        short* __restrict__ xb, short* __restrict__ w1b,
                        short* __restrict__ wob){
  int b = blockIdx.x;
  const float* src; short* dst; int base;
  if (b < 4096)      { src = x;  dst = xb;  base = b; }
  else if (b < 7168) { src = w1; dst = w1b; base = b - 4096; }
  else               { src = wo; dst = wob; base = b - 7168; }
  int i = (base * 256 + threadIdx.x) * 4;
  float4 v = *(const float4*)(src + i);
  short4_t o;
  o.x = (short)f2bf(v.x); o.y = (short)f2bf(v.y);
  o.z = (short)f2bf(v.z); o.w = (short)f2bf(v.w);
  *(short4_t*)(dst + i) = o;
}

// ---------------- QKV GEMM, BK=64 + T2 swizzle: C[4096,3072] = X * W^T
// LDS tiles [128][64] bf16, 8 chunks(16B)/row; chunk c stored linearly, global src
// chunk = c ^ (row&7) (rule-21: linear dest + inv-swz source + swz read).
// Q,K written [b][h][s][64] (Q pre-scaled 1/8); V written TRANSPOSED [b][h][64][s].
__global__ __launch_bounds__(256) void gemm_qkv(
    const short* __restrict__ A, const short* __restrict__ Bw,
    const float* __restrict__ bias,
    short* __restrict__ Qb, short* __restrict__ Kb, short* __restrict__ Vb)
{
  __shared__ short As[128*64], Bs[128*64];
  int tid = threadIdx.x;
  int lane = tid & 63, wv = tid >> 6;
  int wr = wv >> 1, wc = wv & 1;
  int lr = lane & 15, lh = lane >> 4;
  int m0 = blockIdx.y * 128, n0 = blockIdx.x * 128;

  f32x4 acc[4][4] = {};
  for (int kt = 0; kt < K_DIM; kt += 64) {
    #pragma unroll
    for (int j = 0; j < 4; ++j) {
      int off = j*256 + tid;
      int lrow = off >> 3, slin = off & 7;
      int sg = slin ^ (lrow & 7);
      async16(&As[lrow*64 + slin*8], A  + (size_t)(m0+lrow)*K_DIM + kt + sg*8);
      async16(&Bs[lrow*64 + slin*8], Bw + (size_t)(n0+lrow)*K_DIM + kt + sg*8);
    }
    __syncthreads();
    short8 af[4][2], bfr[4][2];
    #pragma unroll
    for (int m = 0; m < 4; ++m)
      #pragma unroll
      for (int kk = 0; kk < 2; ++kk)
        af[m][kk]  = *(const short8*)&As[(wr*64 + m*16 + lr)*64 + (((kk*4 + lh) ^ (lr & 7))*8)];
    #pragma unroll
    for (int n = 0; n < 4; ++n)
      #pragma unroll
      for (int kk = 0; kk < 2; ++kk)
        bfr[n][kk] = *(const short8*)&Bs[(wc*64 + n*16 + lr)*64 + (((kk*4 + lh) ^ (lr & 7))*8)];
    #pragma unroll
    for (int m = 0; m < 4; ++m)
      #pragma unroll
      for (int n = 0; n < 4; ++n)
        #pragma unroll
        for (int kk = 0; kk < 2; ++kk)
          acc[m][n] = __builtin_amdgcn_mfma_f32_16x16x32_bf16(af[m][kk], bfr[n][kk], acc[m][n], 0, 0, 0);
    __syncthreads();
  }
  #pragma unroll
  for (int m = 0; m < 4; ++m) {
    #pragma unroll
    for (int n = 0; n < 4; ++n) {
      int col = n0 + wc*64 + n*16 + lr;
      float bv = bias[col];
      int which = col >> 10, cc = col & 1023;
      int h = cc >> 6, d = cc & 63;
      float scl = which == 0 ? 0.125f : 1.0f;   // fold 1/sqrt(Dh) into Q
      int growb = m0 + wr*64 + m*16 + lh*4;     // 4-aligned, same b for r=0..3
      int b = growb >> 11, s0 = growb & 2047;
      if (which == 2) {
        short4_t vv;                             // pack 4 consecutive s
        vv.x = (short)f2bf(acc[m][n][0] + bv);
        vv.y = (short)f2bf(acc[m][n][1] + bv);
        vv.z = (short)f2bf(acc[m][n][2] + bv);
        vv.w = (short)f2bf(acc[m][n][3] + bv);
        *(short4_t*)&Vb[((size_t)(b*NH + h)*DH + d)*S_LEN + s0] = vv;   // V^T
      } else {
        short* dst = which == 0 ? Qb : Kb;
        #pragma unroll
        for (int r = 0; r < 4; ++r) {
          float v = (acc[m][n][r] + bv) * scl;
          dst[(((size_t)b*NH + h)*S_LEN + s0 + r)*DH + d] = (short)f2bf(v);
        }
      }
    }
  }
}

// ---------------- Out GEMM, 8-wave 128^2 BK=64 swizzled:
// Out[4096,1024] = Attn[4096,1024] * Wo^T + bo (fp32 out).
__global__ __launch_bounds__(512) void gemm_out(
    const short* __restrict__ A, const short* __restrict__ Bw,
    const float* __restrict__ bias, float* __restrict__ Out)
{
  __shared__ short As[128*64], Bs[128*64];
  int tid = threadIdx.x;
  int lane = tid & 63, wv = tid >> 6;        // 8 waves
  int wr = wv >> 2, wc = wv & 3;             // 2 x 4
  int lr = lane & 15, lh = lane >> 4;
  int m0 = blockIdx.y * 128, n0 = blockIdx.x * 128;

  f32x4 acc[4][2] = {};
  for (int kt = 0; kt < K_DIM; kt += 64) {
    #pragma unroll
    for (int j = 0; j < 2; ++j) {
      int off = j*512 + tid;
      int lrow = off >> 3, slin = off & 7;
      int sg = slin ^ (lrow & 7);
      async16(&As[lrow*64 + slin*8], A  + (size_t)(m0+lrow)*K_DIM + kt + sg*8);
      async16(&Bs[lrow*64 + slin*8], Bw + (size_t)(n0+lrow)*K_DIM + kt + sg*8);
    }
    __syncthreads();
    short8 af[4][2], bfr[2][2];
    #pragma unroll
    for (int m = 0; m < 4; ++m)
      #pragma unroll
      for (int kk = 0; kk < 2; ++kk)
        af[m][kk]  = *(const short8*)&As[(wr*64 + m*16 + lr)*64 + (((kk*4 + lh) ^ (lr & 7))*8)];
    #pragma unroll
    for (int n = 0; n < 2; ++n)
      #pragma unroll
      for (int kk = 0; kk < 2; ++kk)
        bfr[n][kk] = *(const short8*)&Bs[(wc*32 + n*16 + lr)*64 + (((kk*4 + lh) ^ (lr & 7))*8)];
    #pragma unroll
    for (int m = 0; m < 4; ++m)
      #pragma unroll
      for (int n = 0; n < 2; ++n)
        #pragma unroll
        for (int kk = 0; kk < 2; ++kk)
          acc[m][n] = __builtin_amdgcn_mfma_f32_16x16x32_bf16(af[m][kk], bfr[n][kk], acc[m][n], 0, 0, 0);
    __syncthreads();
  }
  #pragma unroll
  for (int m = 0; m < 4; ++m) {
    #pragma unroll
    for (int n = 0; n < 2; ++n) {
      int col = n0 + wc*32 + n*16 + lr;
      float bv = bias[col];
      #pragma unroll
      for (int r = 0; r < 4; ++r) {
        int grow = m0 + wr*64 + m*16 + lh*4 + r;
        Out[(size_t)grow*DM + col] = acc[m][n][r] + bv;
      }
    }
  }
}

// ---------------- MFMA flash attention, LDS-free, swapped operands (r2-verified).
__global__ __launch_bounds__(256) void attn_mfma(
    const short* __restrict__ Qb, const short* __restrict__ Kb,
    const short* __restrict__ VTb, short* __restrict__ Ob)
{
  int tid = threadIdx.x;
  int lane = tid & 63, wv = tid >> 6;
  int q31 = lane & 31, h2 = lane >> 5;
  int bh = blockIdx.y;
  int q0w = blockIdx.x * 128 + wv * 32;
  int qa = q0w + q31;

  const short* Qg = Qb  + (size_t)bh * S_LEN * DH;
  const short* Kg = Kb  + (size_t)bh * S_LEN * DH;
  const short* Vg = VTb + (size_t)bh * DH * S_LEN;

  short8 qf[4];
  #pragma unroll
  for (int kc = 0; kc < 4; ++kc)
    qf[kc] = *(const short8*)(Qg + (size_t)qa * DH + kc*16 + h2*8);

  int ks = q0w - WIN; if (ks < 0) ks = 0;
  int ke = q0w + 32 + WIN; if (ke > S_LEN) ke = S_LEN;

  f32x16 o0 = {}, o1 = {};
  float m = -1e37f, l = 0.f;

  for (int t0 = ks; t0 < ke; t0 += 32) {
    f32x16 s = {};
    #pragma unroll
    for (int kc = 0; kc < 4; ++kc) {
      short8 kf = *(const short8*)(Kg + (size_t)(t0 + q31) * DH + kc*16 + h2*8);
      s = __builtin_amdgcn_mfma_f32_32x32x16_bf16(kf, qf[kc], s, 0, 0, 0);
    }
    float p[16];
    float tm = -1e38f;
    #pragma unroll
    for (int r = 0; r < 16; ++r) {
      int key = t0 + (r & 3) + 8*(r >> 2) + 4*h2;
      bool ok = (key >= qa - WIN) && (key <= qa + WIN);
      p[r] = ok ? s[r] : -1e38f;
      tm = fmaxf(tm, p[r]);
    }
    tm = fmaxf(tm, __shfl_xor(tm, 32, 64));
    float mn = fmaxf(m, tm);
    float sc = __expf(m - mn);
    float ts = 0.f;
    #pragma unroll
    for (int r = 0; r < 16; ++r) { p[r] = __expf(p[r] - mn); ts += p[r]; }
    ts += __shfl_xor(ts, 32, 64);
    l = l * sc + ts;
    m = mn;
    #pragma unroll
    for (int r = 0; r < 16; ++r) { o0[r] *= sc; o1[r] *= sc; }

    #pragma unroll
    for (int kc2 = 0; kc2 < 2; ++kc2) {
      unsigned A1 = pk2(p[kc2*8+0], p[kc2*8+1]);
      unsigned A2 = pk2(p[kc2*8+2], p[kc2*8+3]);
      unsigned B1 = pk2(p[kc2*8+4], p[kc2*8+5]);
      unsigned B2 = pk2(p[kc2*8+6], p[kc2*8+7]);
      unsigned sA1 = (unsigned)__shfl_xor((int)A1, 32, 64);
      unsigned sA2 = (unsigned)__shfl_xor((int)A2, 32, 64);
      unsigned sB1 = (unsigned)__shfl_xor((int)B1, 32, 64);
      unsigned sB2 = (unsigned)__shfl_xor((int)B2, 32, 64);
      union { unsigned u[4]; short8 v; } pa;
      pa.u[0] = h2 ? sB1 : A1;
      pa.u[1] = h2 ? sB2 : A2;
      pa.u[2] = h2 ? B1 : sA1;
      pa.u[3] = h2 ? B2 : sA2;
      #pragma unroll
      for (int mt = 0; mt < 2; ++mt) {
        short8 vf = *(const short8*)(Vg + (size_t)(mt*32 + q31) * S_LEN + t0 + kc2*16 + h2*8);
        if (mt == 0) o0 = __builtin_amdgcn_mfma_f32_32x32x16_bf16(vf, pa.v, o0, 0, 0, 0);
        else         o1 = __builtin_amdgcn_mfma_f32_32x32x16_bf16(vf, pa.v, o1, 0, 0, 0);
      }
    }
  }

  float inv = 1.0f / l;
  int b = bh >> 4, hh = bh & 15;
  unsigned* Orow = (unsigned*)Ob + ((size_t)b*S_LEN + qa) * (DM/2) + hh*32;
  #pragma unroll
  for (int mt = 0; mt < 2; ++mt) {
    #pragma unroll
    for (int aa = 0; aa < 4; ++aa) {
      #pragma unroll
      for (int e = 0; e < 2; ++e) {
        int r = 4*aa + 2*e;
        float x0 = (mt ? o1[r]   : o0[r])   * inv;
        float x1 = (mt ? o1[r+1] : o0[r+1]) * inv;
        int d = 2*e + 8*aa + 4*h2 + 32*mt;
        Orow[d >> 1] = pk2(x0, x1);
      }
    }
  }
}

extern "C" void kernel_launch(void* const* d_in, const int* in_sizes, int n_in,
                              void* d_out, int out_size, void* d_ws, size_t ws_size,
                              hipStream_t stream) {
  const float* x  = (const float*)d_in[0];   // [2,2048,1024]
  const float* w1 = (const float*)d_in[1];   // [3072,1024]
  const float* b1 = (const float*)d_in[2];   // [3072]
  const float* wo = (const float*)d_in[3];   // [1024,1024]
  const float* bo = (const float*)d_in[4];   // [1024]
  float* out = (float*)d_out;

  char* ws = (char*)d_ws;
  short* xb  = (short*)(ws);
  short* w1b = (short*)(ws + (size_t)8*1024*1024);
  short* wob = (short*)(ws + (size_t)14*1024*1024);
  short* Qb  = (short*)(ws + (size_t)16*1024*1024);
  short* Kb  = (short*)(ws + (size_t)24*1024*1024);
  short* VTb = (short*)(ws + (size_t)32*1024*1024);
  short* Ab  = (short*)(ws + (size_t)40*1024*1024);

  cvt_all<<<dim3(8192), dim3(256), 0, stream>>>(x, w1, wo, xb, w1b, wob);
  gemm_qkv<<<dim3(24, 32), dim3(256), 0, stream>>>(xb, w1b, b1, Qb, Kb, VTb);
  attn_mfma<<<dim3(16, 32), dim3(256), 0, stream>>>(Qb, Kb, VTb, Ab);
  gemm_out<<<dim3(8, 32), dim3(512), 0, stream>>>(Ab, wob, bo, out);
}

// Round 9
// 168.175 us; speedup vs baseline: 1.0185x; 1.0185x over previous
//
#include <hip/hip_runtime.h>
#include <hip/hip_bf16.h>

// LocalAttention: BK=64 swizzled 128^2 bf16 MFMA GEMMs + LDS-free MFMA flash attn.
// r8: qkv 49.3us (control, unchanged). r9: gemm_out 128x64 512-blk + XCD swz; attn setprio.
// ws layout (bytes): xb[0,8M) w1b[8M,14M) wob[14M,16M) Q[16M,24M) K[24M,32M)
//                    VT[32M,40M) attn[40M,48M)   -- all bf16 (short)

#define S_LEN 2048
#define NH 16
#define DH 64
#define DM 1024
#define WIN 128
#define K_DIM 1024

typedef __attribute__((ext_vector_type(8))) short short8;
typedef __attribute__((ext_vector_type(4))) short short4_t;
typedef __attribute__((ext_vector_type(4))) float f32x4;
typedef __attribute__((ext_vector_type(16))) float f32x16;

__device__ __forceinline__ unsigned short f2bf(float f){
  unsigned u = __float_as_uint(f);
  u += 0x7fffu + ((u >> 16) & 1u);   // RTNE
  return (unsigned short)(u >> 16);
}
__device__ __forceinline__ unsigned pk2(float lo, float hi){
  __hip_bfloat162 h = __float22bfloat162_rn(float2{lo, hi});
  return *reinterpret_cast<unsigned*>(&h);   // v_cvt_pk_bf16_f32
}
__device__ __forceinline__ void async16(void* l, const void* g){
  __builtin_amdgcn_global_load_lds((const __attribute__((address_space(1))) void*)g,
                                   (__attribute__((address_space(3))) void*)l, 16, 0, 0);
}

// ---------------- fused fp32->bf16 converts (exact ranges, no tail)  [CONTROL]
__global__ void cvt_all(const float* __restrict__ x, const float* __restrict__ w1,
                        const float* __restrict__ wo,
                        short* __restrict__ xb, short* __restrict__ w1b,
                        short* __restrict__ wob){
  int b = blockIdx.x;
  const float* src; short* dst; int base;
  if (b < 4096)      { src = x;  dst = xb;  base = b; }
  else if (b < 7168) { src = w1; dst = w1b; base = b - 4096; }
  else               { src = wo; dst = wob; base = b - 7168; }
  int i = (base * 256 + threadIdx.x) * 4;
  float4 v = *(const float4*)(src + i);
  short4_t o;
  o.x = (short)f2bf(v.x); o.y = (short)f2bf(v.y);
  o.z = (short)f2bf(v.z); o.w = (short)f2bf(v.w);
  *(short4_t*)(dst + i) = o;
}

// ---------------- QKV GEMM, BK=64 + T2 swizzle  [CONTROL — r8-measured 49.3us]
__global__ __launch_bounds__(256) void gemm_qkv(
    const short* __restrict__ A, const short* __restrict__ Bw,
    const float* __restrict__ bias,
    short* __restrict__ Qb, short* __restrict__ Kb, short* __restrict__ Vb)
{
  __shared__ short As[128*64], Bs[128*64];
  int tid = threadIdx.x;
  int lane = tid & 63, wv = tid >> 6;
  int wr = wv >> 1, wc = wv & 1;
  int lr = lane & 15, lh = lane >> 4;
  int m0 = blockIdx.y * 128, n0 = blockIdx.x * 128;

  f32x4 acc[4][4] = {};
  for (int kt = 0; kt < K_DIM; kt += 64) {
    #pragma unroll
    for (int j = 0; j < 4; ++j) {
      int off = j*256 + tid;
      int lrow = off >> 3, slin = off & 7;
      int sg = slin ^ (lrow & 7);
      async16(&As[lrow*64 + slin*8], A  + (size_t)(m0+lrow)*K_DIM + kt + sg*8);
      async16(&Bs[lrow*64 + slin*8], Bw + (size_t)(n0+lrow)*K_DIM + kt + sg*8);
    }
    __syncthreads();
    short8 af[4][2], bfr[4][2];
    #pragma unroll
    for (int m = 0; m < 4; ++m)
      #pragma unroll
      for (int kk = 0; kk < 2; ++kk)
        af[m][kk]  = *(const short8*)&As[(wr*64 + m*16 + lr)*64 + (((kk*4 + lh) ^ (lr & 7))*8)];
    #pragma unroll
    for (int n = 0; n < 4; ++n)
      #pragma unroll
      for (int kk = 0; kk < 2; ++kk)
        bfr[n][kk] = *(const short8*)&Bs[(wc*64 + n*16 + lr)*64 + (((kk*4 + lh) ^ (lr & 7))*8)];
    #pragma unroll
    for (int m = 0; m < 4; ++m)
      #pragma unroll
      for (int n = 0; n < 4; ++n)
        #pragma unroll
        for (int kk = 0; kk < 2; ++kk)
          acc[m][n] = __builtin_amdgcn_mfma_f32_16x16x32_bf16(af[m][kk], bfr[n][kk], acc[m][n], 0, 0, 0);
    __syncthreads();
  }
  #pragma unroll
  for (int m = 0; m < 4; ++m) {
    #pragma unroll
    for (int n = 0; n < 4; ++n) {
      int col = n0 + wc*64 + n*16 + lr;
      float bv = bias[col];
      int which = col >> 10, cc = col & 1023;
      int h = cc >> 6, d = cc & 63;
      float scl = which == 0 ? 0.125f : 1.0f;   // fold 1/sqrt(Dh) into Q
      int growb = m0 + wr*64 + m*16 + lh*4;     // 4-aligned, same b for r=0..3
      int b = growb >> 11, s0 = growb & 2047;
      if (which == 2) {
        short4_t vv;                             // pack 4 consecutive s
        vv.x = (short)f2bf(acc[m][n][0] + bv);
        vv.y = (short)f2bf(acc[m][n][1] + bv);
        vv.z = (short)f2bf(acc[m][n][2] + bv);
        vv.w = (short)f2bf(acc[m][n][3] + bv);
        *(short4_t*)&Vb[((size_t)(b*NH + h)*DH + d)*S_LEN + s0] = vv;   // V^T
      } else {
        short* dst = which == 0 ? Qb : Kb;
        #pragma unroll
        for (int r = 0; r < 4; ++r) {
          float v = (acc[m][n][r] + bv) * scl;
          dst[(((size_t)b*NH + h)*S_LEN + s0 + r)*DH + d] = (short)f2bf(v);
        }
      }
    }
  }
}

// ---------------- Out GEMM, 128x64 tiles, 512 blocks (2/CU), 4 waves, BK=64 swz,
// XCD-chunked block swizzle (bijective: 512 = 8 XCD x 64 chunks).
__global__ __launch_bounds__(256) void gemm_out(
    const short* __restrict__ A, const short* __restrict__ Bw,
    const float* __restrict__ bias, float* __restrict__ Out)
{
  __shared__ short As[128*64], Bs[64*64];
  int tid = threadIdx.x;
  int lane = tid & 63, wv = tid >> 6;        // 4 waves
  int wr = wv >> 1, wc = wv & 1;             // 2 x 2
  int lr = lane & 15, lh = lane >> 4;
  int bid = blockIdx.x + blockIdx.y * 16;    // linear, 0..511
  int swz = (bid & 7) * 64 + (bid >> 3);     // XCD-chunked, bijective
  int nt = swz & 15, mt = swz >> 4;
  int m0 = mt * 128, n0 = nt * 64;

  f32x4 acc[4][2] = {};
  for (int kt = 0; kt < K_DIM; kt += 64) {
    #pragma unroll
    for (int j = 0; j < 4; ++j) {            // A: 128 rows
      int off = j*256 + tid;
      int lrow = off >> 3, slin = off & 7;
      int sg = slin ^ (lrow & 7);
      async16(&As[lrow*64 + slin*8], A + (size_t)(m0+lrow)*K_DIM + kt + sg*8);
    }
    #pragma unroll
    for (int j = 0; j < 2; ++j) {            // B: 64 rows
      int off = j*256 + tid;
      int lrow = off >> 3, slin = off & 7;
      int sg = slin ^ (lrow & 7);
      async16(&Bs[lrow*64 + slin*8], Bw + (size_t)(n0+lrow)*K_DIM + kt + sg*8);
    }
    __syncthreads();
    short8 af[4][2], bfr[2][2];
    #pragma unroll
    for (int m = 0; m < 4; ++m)
      #pragma unroll
      for (int kk = 0; kk < 2; ++kk)
        af[m][kk]  = *(const short8*)&As[(wr*64 + m*16 + lr)*64 + (((kk*4 + lh) ^ (lr & 7))*8)];
    #pragma unroll
    for (int n = 0; n < 2; ++n)
      #pragma unroll
      for (int kk = 0; kk < 2; ++kk)
        bfr[n][kk] = *(const short8*)&Bs[(wc*32 + n*16 + lr)*64 + (((kk*4 + lh) ^ (lr & 7))*8)];
    #pragma unroll
    for (int m = 0; m < 4; ++m)
      #pragma unroll
      for (int n = 0; n < 2; ++n)
        #pragma unroll
        for (int kk = 0; kk < 2; ++kk)
          acc[m][n] = __builtin_amdgcn_mfma_f32_16x16x32_bf16(af[m][kk], bfr[n][kk], acc[m][n], 0, 0, 0);
    __syncthreads();
  }
  #pragma unroll
  for (int m = 0; m < 4; ++m) {
    #pragma unroll
    for (int n = 0; n < 2; ++n) {
      int col = n0 + wc*32 + n*16 + lr;
      float bv = bias[col];
      #pragma unroll
      for (int r = 0; r < 4; ++r) {
        int grow = m0 + wr*64 + m*16 + lh*4 + r;
        Out[(size_t)grow*DM + col] = acc[m][n][r] + bv;
      }
    }
  }
}

// ---------------- MFMA flash attention, LDS-free, swapped operands (r2-verified)
// + T5 setprio around MFMA clusters (independent waves, non-lockstep regime).
__global__ __launch_bounds__(256) void attn_mfma(
    const short* __restrict__ Qb, const short* __restrict__ Kb,
    const short* __restrict__ VTb, short* __restrict__ Ob)
{
  int tid = threadIdx.x;
  int lane = tid & 63, wv = tid >> 6;
  int q31 = lane & 31, h2 = lane >> 5;
  int bh = blockIdx.y;
  int q0w = blockIdx.x * 128 + wv * 32;
  int qa = q0w + q31;

  const short* Qg = Qb  + (size_t)bh * S_LEN * DH;
  const short* Kg = Kb  + (size_t)bh * S_LEN * DH;
  const short* Vg = VTb + (size_t)bh * DH * S_LEN;

  short8 qf[4];
  #pragma unroll
  for (int kc = 0; kc < 4; ++kc)
    qf[kc] = *(const short8*)(Qg + (size_t)qa * DH + kc*16 + h2*8);

  int ks = q0w - WIN; if (ks < 0) ks = 0;
  int ke = q0w + 32 + WIN; if (ke > S_LEN) ke = S_LEN;

  f32x16 o0 = {}, o1 = {};
  float m = -1e37f, l = 0.f;

  for (int t0 = ks; t0 < ke; t0 += 32) {
    short8 kf[4];
    #pragma unroll
    for (int kc = 0; kc < 4; ++kc)
      kf[kc] = *(const short8*)(Kg + (size_t)(t0 + q31) * DH + kc*16 + h2*8);
    f32x16 s = {};
    __builtin_amdgcn_s_setprio(1);
    #pragma unroll
    for (int kc = 0; kc < 4; ++kc)
      s = __builtin_amdgcn_mfma_f32_32x32x16_bf16(kf[kc], qf[kc], s, 0, 0, 0);
    __builtin_amdgcn_s_setprio(0);
    float p[16];
    float tm = -1e38f;
    #pragma unroll
    for (int r = 0; r < 16; ++r) {
      int key = t0 + (r & 3) + 8*(r >> 2) + 4*h2;
      bool ok = (key >= qa - WIN) && (key <= qa + WIN);
      p[r] = ok ? s[r] : -1e38f;
      tm = fmaxf(tm, p[r]);
    }
    tm = fmaxf(tm, __shfl_xor(tm, 32, 64));
    float mn = fmaxf(m, tm);
    float sc = __expf(m - mn);
    float ts = 0.f;
    #pragma unroll
    for (int r = 0; r < 16; ++r) { p[r] = __expf(p[r] - mn); ts += p[r]; }
    ts += __shfl_xor(ts, 32, 64);
    l = l * sc + ts;
    m = mn;
    #pragma unroll
    for (int r = 0; r < 16; ++r) { o0[r] *= sc; o1[r] *= sc; }

    #pragma unroll
    for (int kc2 = 0; kc2 < 2; ++kc2) {
      unsigned A1 = pk2(p[kc2*8+0], p[kc2*8+1]);
      unsigned A2 = pk2(p[kc2*8+2], p[kc2*8+3]);
      unsigned B1 = pk2(p[kc2*8+4], p[kc2*8+5]);
      unsigned B2 = pk2(p[kc2*8+6], p[kc2*8+7]);
      unsigned sA1 = (unsigned)__shfl_xor((int)A1, 32, 64);
      unsigned sA2 = (unsigned)__shfl_xor((int)A2, 32, 64);
      unsigned sB1 = (unsigned)__shfl_xor((int)B1, 32, 64);
      unsigned sB2 = (unsigned)__shfl_xor((int)B2, 32, 64);
      union { unsigned u[4]; short8 v; } pa;
      pa.u[0] = h2 ? sB1 : A1;
      pa.u[1] = h2 ? sB2 : A2;
      pa.u[2] = h2 ? B1 : sA1;
      pa.u[3] = h2 ? B2 : sA2;
      short8 vf0 = *(const short8*)(Vg + (size_t)q31 * S_LEN + t0 + kc2*16 + h2*8);
      short8 vf1 = *(const short8*)(Vg + (size_t)(32 + q31) * S_LEN + t0 + kc2*16 + h2*8);
      __builtin_amdgcn_s_setprio(1);
      o0 = __builtin_amdgcn_mfma_f32_32x32x16_bf16(vf0, pa.v, o0, 0, 0, 0);
      o1 = __builtin_amdgcn_mfma_f32_32x32x16_bf16(vf1, pa.v, o1, 0, 0, 0);
      __builtin_amdgcn_s_setprio(0);
    }
  }

  float inv = 1.0f / l;
  int b = bh >> 4, hh = bh & 15;
  unsigned* Orow = (unsigned*)Ob + ((size_t)b*S_LEN + qa) * (DM/2) + hh*32;
  #pragma unroll
  for (int mt = 0; mt < 2; ++mt) {
    #pragma unroll
    for (int aa = 0; aa < 4; ++aa) {
      #pragma unroll
      for (int e = 0; e < 2; ++e) {
        int r = 4*aa + 2*e;
        float x0 = (mt ? o1[r]   : o0[r])   * inv;
        float x1 = (mt ? o1[r+1] : o0[r+1]) * inv;
        int d = 2*e + 8*aa + 4*h2 + 32*mt;
        Orow[d >> 1] = pk2(x0, x1);
      }
    }
  }
}

extern "C" void kernel_launch(void* const* d_in, const int* in_sizes, int n_in,
                              void* d_out, int out_size, void* d_ws, size_t ws_size,
                              hipStream_t stream) {
  const float* x  = (const float*)d_in[0];   // [2,2048,1024]
  const float* w1 = (const float*)d_in[1];   // [3072,1024]
  const float* b1 = (const float*)d_in[2];   // [3072]
  const float* wo = (const float*)d_in[3];   // [1024,1024]
  const float* bo = (const float*)d_in[4];   // [1024]
  float* out = (float*)d_out;

  char* ws = (char*)d_ws;
  short* xb  = (short*)(ws);
  short* w1b = (short*)(ws + (size_t)8*1024*1024);
  short* wob = (short*)(ws + (size_t)14*1024*1024);
  short* Qb  = (short*)(ws + (size_t)16*1024*1024);
  short* Kb  = (short*)(ws + (size_t)24*1024*1024);
  short* VTb = (short*)(ws + (size_t)32*1024*1024);
  short* Ab  = (short*)(ws + (size_t)40*1024*1024);

  cvt_all<<<dim3(8192), dim3(256), 0, stream>>>(x, w1, wo, xb, w1b, wob);
  gemm_qkv<<<dim3(24, 32), dim3(256), 0, stream>>>(xb, w1b, b1, Qb, Kb, VTb);
  attn_mfma<<<dim3(16, 32), dim3(256), 0, stream>>>(Qb, Kb, VTb, Ab);
  gemm_out<<<dim3(16, 32), dim3(256), 0, stream>>>(Ab, wob, bo, out);
}